// Round 18
// baseline (1528.366 us; speedup 1.0000x reference)
//
#include <hip/hip_runtime.h>
#include <cstdint>

constexpr int Bc = 2, Sc = 2048, Hc = 1024, NHc = 16, HDc = 64, PFc = 4096, Lc = 6;
constexpr float EPSc = 1e-5f;
constexpr float QSC = 0.18033688011112042f;   // 0.125 * log2(e)

using f32x4  = __attribute__((ext_vector_type(4))) float;
using bf16x8 = __attribute__((ext_vector_type(8))) __bf16;
using bf16x4 = __attribute__((ext_vector_type(4))) __bf16;
using u32x4  = __attribute__((ext_vector_type(4))) unsigned;

#if __has_builtin(__builtin_amdgcn_exp2f)
#define EXP2(x) __builtin_amdgcn_exp2f(x)
#else
#define EXP2(x) exp2f(x)
#endif

__device__ __forceinline__ f32x4 mfma16(bf16x8 a, bf16x8 b, f32x4 c) {
    return __builtin_amdgcn_mfma_f32_16x16x32_bf16(a, b, c, 0, 0, 0);
}

__device__ __forceinline__ void gload_lds16(const void* g, void* l) {
    __builtin_amdgcn_global_load_lds(
        (__attribute__((address_space(1))) void*)(uintptr_t)g,
        (__attribute__((address_space(3))) void*)(uint32_t)(uintptr_t)l,
        16, 0, 0);
}

// counted vmcnt wait (T4): leave N newest loads in flight
template<int N> __device__ __forceinline__ void wait_vmcnt() {
    if constexpr (N == 0)      asm volatile("s_waitcnt vmcnt(0)" ::: "memory");
    else if constexpr (N == 6) asm volatile("s_waitcnt vmcnt(6)" ::: "memory");
    else if constexpr (N == 8) asm volatile("s_waitcnt vmcnt(8)" ::: "memory");
}
__device__ __forceinline__ void wait_lgkm0() {
    asm volatile("s_waitcnt lgkmcnt(0)" ::: "memory");
    __builtin_amdgcn_sched_barrier(0);   // rule 18: fence MFMA hoisting
}

struct HL { __bf16 h, l; };
__device__ __forceinline__ HL split2(float v) {
    HL r;
    r.h = (__bf16)v;
    r.l = (__bf16)(v - (float)r.h);
    return r;
}

__device__ __forceinline__ unsigned bfbits(__bf16 x) {
    return (unsigned)__builtin_bit_cast(unsigned short, x);
}
__device__ __forceinline__ unsigned packbf(float a, float b) {
    return bfbits((__bf16)a) | (bfbits((__bf16)b) << 16);
}

// XCD-aware bijective block swizzle (requires nwg % 8 == 0)
__device__ __forceinline__ int xcd_swz(int bid, int nwg) {
    return (bid & 7) * (nwg >> 3) + (bid >> 3);
}

// ---------------------------------------------------------------------------
// Weight convert: f32 [K][N] -> bf16 [N][K], 64x64 tiles via LDS.
// ---------------------------------------------------------------------------
__global__ __launch_bounds__(256) void wconv_kernel(
    const float* __restrict__ in, __bf16* __restrict__ out, int K, int N)
{
    __shared__ float tile[64][65];
    const int t = threadIdx.x;
    const size_t lstride = (size_t)K * N;
    const float* ip = in + (size_t)blockIdx.z * lstride;
    __bf16* op = out + (size_t)blockIdx.z * lstride;
    const int n0 = blockIdx.x * 64, k0 = blockIdx.y * 64;
    #pragma unroll
    for (int c = 0; c < 4; ++c) {
        int idx = c * 256 + t;
        int row = idx >> 4;
        int c4  = idx & 15;
        float4 v = *(const float4*)(ip + (size_t)(k0 + row) * N + n0 + c4 * 4);
        tile[row][c4 * 4 + 0] = v.x; tile[row][c4 * 4 + 1] = v.y;
        tile[row][c4 * 4 + 2] = v.z; tile[row][c4 * 4 + 3] = v.w;
    }
    __syncthreads();
    #pragma unroll
    for (int c = 0; c < 4; ++c) {
        int idx = c * 256 + t;
        int n  = idx >> 4;
        int k4 = idx & 15;
        bf16x4 hh = { (__bf16)tile[k4 * 4 + 0][n], (__bf16)tile[k4 * 4 + 1][n],
                      (__bf16)tile[k4 * 4 + 2][n], (__bf16)tile[k4 * 4 + 3][n] };
        *(bf16x4*)(op + (size_t)(n0 + n) * K + k0 + k4 * 4) = hh;
    }
}

// ---------------------------------------------------------------------------
// Weight convert split: f32 [K][N] -> bf16 hi [N][K] + lo [N][K] (layer 0 Q/K)
// ---------------------------------------------------------------------------
__global__ __launch_bounds__(256) void wconv2_kernel(
    const float* __restrict__ in, __bf16* __restrict__ outh,
    __bf16* __restrict__ outl, int K, int N)
{
    __shared__ float tile[64][65];
    const int t = threadIdx.x;
    const int n0 = blockIdx.x * 64, k0 = blockIdx.y * 64;
    #pragma unroll
    for (int c = 0; c < 4; ++c) {
        int idx = c * 256 + t;
        int row = idx >> 4;
        int c4  = idx & 15;
        float4 v = *(const float4*)(in + (size_t)(k0 + row) * N + n0 + c4 * 4);
        tile[row][c4 * 4 + 0] = v.x; tile[row][c4 * 4 + 1] = v.y;
        tile[row][c4 * 4 + 2] = v.z; tile[row][c4 * 4 + 3] = v.w;
    }
    __syncthreads();
    #pragma unroll
    for (int c = 0; c < 4; ++c) {
        int idx = c * 256 + t;
        int n  = idx >> 4;
        int k4 = idx & 15;
        HL e0 = split2(tile[k4 * 4 + 0][n]);
        HL e1 = split2(tile[k4 * 4 + 1][n]);
        HL e2 = split2(tile[k4 * 4 + 2][n]);
        HL e3 = split2(tile[k4 * 4 + 3][n]);
        bf16x4 hh = { e0.h, e1.h, e2.h, e3.h };
        bf16x4 ll = { e0.l, e1.l, e2.l, e3.l };
        *(bf16x4*)(outh + (size_t)(n0 + n) * K + k0 + k4 * 4) = hh;
        *(bf16x4*)(outl + (size_t)(n0 + n) * K + k0 + k4 * 4) = ll;
    }
}

// ---------------------------------------------------------------------------
// Embed: src = in*32 + pos ; f32 master + split bf16
// ---------------------------------------------------------------------------
__global__ __launch_bounds__(256) void embed_kernel(
    const float* __restrict__ in, const float* __restrict__ pos,
    float* __restrict__ sf, __bf16* __restrict__ sh, __bf16* __restrict__ sl)
{
    const int n4 = (Bc * Sc * Hc) / 4;
    const int pmask = (Sc * Hc / 4) - 1;
    for (int i = blockIdx.x * 256 + threadIdx.x; i < n4; i += gridDim.x * 256) {
        float4 a = ((const float4*)in)[i];
        float4 p = ((const float4*)pos)[i & pmask];
        float4 r;
        r.x = a.x * 32.f + p.x; r.y = a.y * 32.f + p.y;
        r.z = a.z * 32.f + p.z; r.w = a.w * 32.f + p.w;
        ((float4*)sf)[i] = r;
        HL e0 = split2(r.x), e1 = split2(r.y), e2 = split2(r.z), e3 = split2(r.w);
        bf16x4 hh = { e0.h, e1.h, e2.h, e3.h };
        bf16x4 ll = { e0.l, e1.l, e2.l, e3.l };
        ((bf16x4*)sh)[i] = hh;
        ((bf16x4*)sl)[i] = ll;
    }
}

// ---------------------------------------------------------------------------
// GEMM on pre-transposed bf16 weights. BM x 128 tile, BK=64, 4 waves.
// T4 counted-vmcnt pipeline + XCD swizzle + setprio. OUTMODE: 0=f32, 1=bf16.
// ---------------------------------------------------------------------------
template<int BM, int OUTMODE, bool RELU>
__global__ __launch_bounds__(256) void gemm_bt_kernel(
    const __bf16* __restrict__ A, const __bf16* __restrict__ Wt,
    const float* __restrict__ bias, void* __restrict__ out,
    int M, int N, int K)
{
    constexpr int MI = BM / 32;
    constexpr int LPT = BM / 32 + 4;   // gloads per thread per stage
    __shared__ alignas(16) __bf16 Alds[2][BM * 64];
    __shared__ alignas(16) __bf16 Blds[2][128 * 64];

    const int tid = threadIdx.x, lane = tid & 63, wave = tid >> 6;
    const int lr = lane & 15, lg = lane >> 4;
    const int nbx = gridDim.x;
    const int swz = xcd_swz(blockIdx.y * nbx + blockIdx.x, nbx * gridDim.y);
    const int m0 = (swz / nbx) * BM, n0 = (swz % nbx) * 128;
    const int wm = (wave >> 1) * (BM / 2), wn = (wave & 1) * 64;

    f32x4 acc[MI][4] = {};

    auto stage = [&](int k0, int buf) {
        #pragma unroll
        for (int c = 0; c < BM / 32; ++c) {
            int li = c * 256 + tid;
            int row = li >> 3;
            int lcb = ((li & 7) << 4) ^ ((row & 7) << 4);
            gload_lds16(A + (size_t)(m0 + row) * K + k0 + (lcb >> 1),
                        (char*)Alds[buf] + (size_t)(c * 256 + wave * 64) * 16);
        }
        #pragma unroll
        for (int c = 0; c < 4; ++c) {
            int li = c * 256 + tid;
            int row = li >> 3;
            int lcb = ((li & 7) << 4) ^ ((row & 7) << 4);
            gload_lds16(Wt + (size_t)(n0 + row) * K + k0 + (lcb >> 1),
                        (char*)Blds[buf] + (size_t)(c * 256 + wave * 64) * 16);
        }
    };

    stage(0, 0);
    if (K > 64) stage(64, 1);

    for (int k0 = 0; k0 < K; k0 += 64) {
        const int cur = (k0 >> 6) & 1;
        if (k0 + 64 < K) wait_vmcnt<LPT>();
        else             wait_vmcnt<0>();
        __builtin_amdgcn_s_barrier();

        bf16x8 af[2][MI], bfr[2][4];
        #pragma unroll
        for (int ks = 0; ks < 2; ++ks) {
            #pragma unroll
            for (int i = 0; i < MI; ++i) {
                int ra = wm + i * 16 + lr;
                int pa = (ks * 64 + lg * 16) ^ ((ra & 7) << 4);
                af[ks][i] = *(const bf16x8*)((const char*)Alds[cur] + ra * 128 + pa);
            }
            #pragma unroll
            for (int i = 0; i < 4; ++i) {
                int rb = wn + i * 16 + lr;
                int pb = (ks * 64 + lg * 16) ^ ((rb & 7) << 4);
                bfr[ks][i] = *(const bf16x8*)((const char*)Blds[cur] + rb * 128 + pb);
            }
        }
        wait_lgkm0();
        __builtin_amdgcn_s_barrier();
        if (k0 + 128 < K) stage(k0 + 128, cur);

        __builtin_amdgcn_s_setprio(1);
        #pragma unroll
        for (int ks = 0; ks < 2; ++ks)
            #pragma unroll
            for (int mi = 0; mi < MI; ++mi)
                #pragma unroll
                for (int ni = 0; ni < 4; ++ni)
                    acc[mi][ni] = mfma16(af[ks][mi], bfr[ks][ni], acc[mi][ni]);
        __builtin_amdgcn_s_setprio(0);
    }

    #pragma unroll
    for (int ni = 0; ni < 4; ++ni) {
        int col = n0 + wn + ni * 16 + lr;
        float bv = bias[col];
        #pragma unroll
        for (int mi = 0; mi < MI; ++mi) {
            int rowb = m0 + wm + mi * 16 + lg * 4;
            #pragma unroll
            for (int r = 0; r < 4; ++r) {
                float v = acc[mi][ni][r] + bv;
                if (RELU) v = fmaxf(v, 0.f);
                size_t idx = (size_t)(rowb + r) * N + col;
                if constexpr (OUTMODE == 0) ((float*)out)[idx] = v;
                else                        ((__bf16*)out)[idx] = (__bf16)v;
            }
        }
    }
}

// ---------------------------------------------------------------------------
// Split-K GEMM (BM=64): blockIdx.z selects K-half [z*KL, z*KL+KL). Each half
// writes bf16 to out + z*M*N; bias added in z==0 only. Same T4 pipeline.
// ---------------------------------------------------------------------------
__global__ __launch_bounds__(256) void gemm_btsk_kernel(
    const __bf16* __restrict__ A, const __bf16* __restrict__ Wt,
    const float* __restrict__ bias, __bf16* __restrict__ out,
    int M, int N, int K, int KL)
{
    constexpr int MI = 2;     // BM=64
    constexpr int LPT = 6;
    __shared__ alignas(16) __bf16 Alds[2][64 * 64];
    __shared__ alignas(16) __bf16 Blds[2][128 * 64];

    const int tid = threadIdx.x, lane = tid & 63, wave = tid >> 6;
    const int lr = lane & 15, lg = lane >> 4;
    const int nbx = gridDim.x;
    const int swz = xcd_swz(blockIdx.y * nbx + blockIdx.x, nbx * gridDim.y);
    const int m0 = (swz / nbx) * 64, n0 = (swz % nbx) * 128;
    const int wm = (wave >> 1) * 32, wn = (wave & 1) * 64;
    const int koff = blockIdx.z * KL;
    const int kend = koff + KL;
    __bf16* outz = out + (size_t)blockIdx.z * M * N;

    f32x4 acc[MI][4] = {};

    auto stage = [&](int k0, int buf) {
        #pragma unroll
        for (int c = 0; c < 2; ++c) {
            int li = c * 256 + tid;
            int row = li >> 3;
            int lcb = ((li & 7) << 4) ^ ((row & 7) << 4);
            gload_lds16(A + (size_t)(m0 + row) * K + k0 + (lcb >> 1),
                        (char*)Alds[buf] + (size_t)(c * 256 + wave * 64) * 16);
        }
        #pragma unroll
        for (int c = 0; c < 4; ++c) {
            int li = c * 256 + tid;
            int row = li >> 3;
            int lcb = ((li & 7) << 4) ^ ((row & 7) << 4);
            gload_lds16(Wt + (size_t)(n0 + row) * K + k0 + (lcb >> 1),
                        (char*)Blds[buf] + (size_t)(c * 256 + wave * 64) * 16);
        }
    };

    stage(koff, 0);
    stage(koff + 64, 1);

    for (int k0 = koff; k0 < kend; k0 += 64) {
        const int cur = ((k0 - koff) >> 6) & 1;
        if (k0 + 64 < kend) wait_vmcnt<LPT>();
        else                wait_vmcnt<0>();
        __builtin_amdgcn_s_barrier();

        bf16x8 af[2][MI], bfr[2][4];
        #pragma unroll
        for (int ks = 0; ks < 2; ++ks) {
            #pragma unroll
            for (int i = 0; i < MI; ++i) {
                int ra = wm + i * 16 + lr;
                int pa = (ks * 64 + lg * 16) ^ ((ra & 7) << 4);
                af[ks][i] = *(const bf16x8*)((const char*)Alds[cur] + ra * 128 + pa);
            }
            #pragma unroll
            for (int i = 0; i < 4; ++i) {
                int rb = wn + i * 16 + lr;
                int pb = (ks * 64 + lg * 16) ^ ((rb & 7) << 4);
                bfr[ks][i] = *(const bf16x8*)((const char*)Blds[cur] + rb * 128 + pb);
            }
        }
        wait_lgkm0();
        __builtin_amdgcn_s_barrier();
        if (k0 + 128 < kend) stage(k0 + 128, cur);

        __builtin_amdgcn_s_setprio(1);
        #pragma unroll
        for (int ks = 0; ks < 2; ++ks)
            #pragma unroll
            for (int mi = 0; mi < MI; ++mi)
                #pragma unroll
                for (int ni = 0; ni < 4; ++ni)
                    acc[mi][ni] = mfma16(af[ks][mi], bfr[ks][ni], acc[mi][ni]);
        __builtin_amdgcn_s_setprio(0);
    }

    #pragma unroll
    for (int ni = 0; ni < 4; ++ni) {
        int col = n0 + wn + ni * 16 + lr;
        float bv = (blockIdx.z == 0) ? bias[col] : 0.f;
        #pragma unroll
        for (int mi = 0; mi < MI; ++mi) {
            int rowb = m0 + wm + mi * 16 + lg * 4;
            #pragma unroll
            for (int r = 0; r < 4; ++r)
                outz[(size_t)(rowb + r) * N + col] = (__bf16)(acc[mi][ni][r] + bv);
        }
    }
}

// ---------------------------------------------------------------------------
// Fused QKV on pre-transposed bf16 weights (layers >= 1). Head-major out.
// T4 counted-vmcnt pipeline. q pre-scaled by QSC.
// ---------------------------------------------------------------------------
struct QKVBT {
    const __bf16 *wq, *wk, *wv;
    const float *bq, *bk, *bv;
    __bf16 *q, *k, *v;
};

__global__ __launch_bounds__(256) void qkv_bt_kernel(
    const __bf16* __restrict__ A, QKVBT a)
{
    constexpr int N = Hc, K = Hc;
    constexpr int LPT = 8;
    __shared__ alignas(16) __bf16 Alds[2][128 * 64];
    __shared__ alignas(16) __bf16 Blds[2][128 * 64];

    const int tid = threadIdx.x, lane = tid & 63, wave = tid >> 6;
    const int lr = lane & 15, lg = lane >> 4;
    const int nbx = gridDim.x;
    const int swz = xcd_swz(blockIdx.y * nbx + blockIdx.x, nbx * gridDim.y);
    const int gx = swz % nbx;
    const int widx = gx >> 3;
    const int n0 = (gx & 7) * 128;
    const int m0 = (swz / nbx) * 128;
    const int wm = (wave >> 1) * 64, wn = (wave & 1) * 64;

    const __bf16* Wt  = (widx == 0) ? a.wq : (widx == 1) ? a.wk : a.wv;
    const float* bias = (widx == 0) ? a.bq : (widx == 1) ? a.bk : a.bv;

    f32x4 acc[4][4] = {};

    auto stage = [&](int k0, int buf) {
        #pragma unroll
        for (int c = 0; c < 4; ++c) {
            int li = c * 256 + tid;
            int row = li >> 3;
            int lcb = ((li & 7) << 4) ^ ((row & 7) << 4);
            gload_lds16(A + (size_t)(m0 + row) * K + k0 + (lcb >> 1),
                        (char*)Alds[buf] + (size_t)(c * 256 + wave * 64) * 16);
            gload_lds16(Wt + (size_t)(n0 + row) * K + k0 + (lcb >> 1),
                        (char*)Blds[buf] + (size_t)(c * 256 + wave * 64) * 16);
        }
    };

    stage(0, 0);
    stage(64, 1);

    for (int k0 = 0; k0 < K; k0 += 64) {
        const int cur = (k0 >> 6) & 1;
        if (k0 + 64 < K) wait_vmcnt<LPT>();
        else             wait_vmcnt<0>();
        __builtin_amdgcn_s_barrier();

        bf16x8 af[2][4], bfr[2][4];
        #pragma unroll
        for (int ks = 0; ks < 2; ++ks) {
            #pragma unroll
            for (int i = 0; i < 4; ++i) {
                int ra = wm + i * 16 + lr;
                int pa = (ks * 64 + lg * 16) ^ ((ra & 7) << 4);
                af[ks][i] = *(const bf16x8*)((const char*)Alds[cur] + ra * 128 + pa);
                int rb = wn + i * 16 + lr;
                int pb = (ks * 64 + lg * 16) ^ ((rb & 7) << 4);
                bfr[ks][i] = *(const bf16x8*)((const char*)Blds[cur] + rb * 128 + pb);
            }
        }
        wait_lgkm0();
        __builtin_amdgcn_s_barrier();
        if (k0 + 128 < K) stage(k0 + 128, cur);

        __builtin_amdgcn_s_setprio(1);
        #pragma unroll
        for (int ks = 0; ks < 2; ++ks)
            #pragma unroll
            for (int mi = 0; mi < 4; ++mi)
                #pragma unroll
                for (int ni = 0; ni < 4; ++ni)
                    acc[mi][ni] = mfma16(af[ks][mi], bfr[ks][ni], acc[mi][ni]);
        __builtin_amdgcn_s_setprio(0);
    }

    __bf16* outp = (widx == 0) ? a.q : (widx == 1) ? a.k : a.v;
    const float osc = (widx == 0) ? QSC : 1.f;
    #pragma unroll
    for (int ni = 0; ni < 4; ++ni) {
        int col = n0 + wn + ni * 16 + lr;
        float bv = bias[col];
        int hh = col >> 6, d = col & 63;
        #pragma unroll
        for (int mi = 0; mi < 4; ++mi) {
            int rowb = m0 + wm + mi * 16 + lg * 4;
            #pragma unroll
            for (int r = 0; r < 4; ++r) {
                int row = rowb + r;
                int bb = row >> 11, s = row & (Sc - 1);
                outp[((size_t)(bb * NHc + hh) * Sc + s) * HDc + d] =
                    (__bf16)((acc[mi][ni][r] + bv) * osc);
            }
        }
    }
}

// ---------------------------------------------------------------------------
// Layer-0 QKV, all-gload version. Q,K: split x split (3 MFMA). V plain.
// ---------------------------------------------------------------------------
struct QKV0S {
    const __bf16 *wqh, *wql, *wkh, *wkl, *wv;
    const float *bq, *bk, *bv;
    __bf16 *qh, *ql, *kh, *kl, *vv;
};

__global__ __launch_bounds__(256) void qkv0s_kernel(
    const __bf16* __restrict__ Ahi, const __bf16* __restrict__ Alo, QKV0S a)
{
    constexpr int N = Hc, K = Hc;
    __shared__ alignas(16) __bf16 AldsH[128 * 64];
    __shared__ alignas(16) __bf16 AldsL[128 * 64];
    __shared__ alignas(16) __bf16 BldsH[128 * 64];
    __shared__ alignas(16) __bf16 BldsL[128 * 64];

    const int tid = threadIdx.x, lane = tid & 63, wave = tid >> 6;
    const int lr = lane & 15, lg = lane >> 4;
    const int nbx = gridDim.x;
    const int swz = xcd_swz(blockIdx.y * nbx + blockIdx.x, nbx * gridDim.y);
    const int gx = swz % nbx;
    const int widx = gx >> 3;
    const int n0 = (gx & 7) * 128;
    const int m0 = (swz / nbx) * 128;
    const int wm = (wave >> 1) * 64, wn = (wave & 1) * 64;
    const bool SPLIT = (widx < 2);

    const __bf16* Bh = (widx == 0) ? a.wqh : (widx == 1) ? a.wkh : a.wv;
    const __bf16* Bl = (widx == 0) ? a.wql : a.wkl;
    const float* bias = (widx == 0) ? a.bq : (widx == 1) ? a.bk : a.bv;

    f32x4 acc[4][4] = {};

    for (int k0 = 0; k0 < K; k0 += 64) {
        #pragma unroll
        for (int c = 0; c < 4; ++c) {
            int li = c * 256 + tid;
            int row = li >> 3;
            int lcb = ((li & 7) << 4) ^ ((row & 7) << 4);
            size_t aoff = (size_t)(m0 + row) * K + k0 + (lcb >> 1);
            size_t boff = (size_t)(n0 + row) * K + k0 + (lcb >> 1);
            size_t loff = (size_t)(c * 256 + wave * 64) * 16;
            gload_lds16(Ahi + aoff, (char*)AldsH + loff);
            gload_lds16(Bh + boff, (char*)BldsH + loff);
            if (SPLIT) {
                gload_lds16(Alo + aoff, (char*)AldsL + loff);
                gload_lds16(Bl + boff, (char*)BldsL + loff);
            }
        }
        __syncthreads();

        bf16x8 ah[2][4], al[2][4], bh[2][4], bl[2][4];
        #pragma unroll
        for (int ks = 0; ks < 2; ++ks) {
            #pragma unroll
            for (int i = 0; i < 4; ++i) {
                int ra = wm + i * 16 + lr;
                int pa = (ks * 64 + lg * 16) ^ ((ra & 7) << 4);
                ah[ks][i] = *(const bf16x8*)((const char*)AldsH + ra * 128 + pa);
                int rb = wn + i * 16 + lr;
                int pb = (ks * 64 + lg * 16) ^ ((rb & 7) << 4);
                bh[ks][i] = *(const bf16x8*)((const char*)BldsH + rb * 128 + pb);
                if (SPLIT) {
                    al[ks][i] = *(const bf16x8*)((const char*)AldsL + ra * 128 + pa);
                    bl[ks][i] = *(const bf16x8*)((const char*)BldsL + rb * 128 + pb);
                }
            }
        }
        #pragma unroll
        for (int ks = 0; ks < 2; ++ks)
            #pragma unroll
            for (int mi = 0; mi < 4; ++mi)
                #pragma unroll
                for (int ni = 0; ni < 4; ++ni) {
                    acc[mi][ni] = mfma16(ah[ks][mi], bh[ks][ni], acc[mi][ni]);
                    if (SPLIT) {
                        acc[mi][ni] = mfma16(al[ks][mi], bh[ks][ni], acc[mi][ni]);
                        acc[mi][ni] = mfma16(ah[ks][mi], bl[ks][ni], acc[mi][ni]);
                    }
                }
        __syncthreads();
    }

    __bf16* outh = (widx == 0) ? a.qh : (widx == 1) ? a.kh : a.vv;
    __bf16* outl = (widx == 0) ? a.ql : a.kl;
    const float osc = (widx == 0) ? QSC : 1.f;
    #pragma unroll
    for (int ni = 0; ni < 4; ++ni) {
        int col = n0 + wn + ni * 16 + lr;
        float bv = bias[col];
        int hh = col >> 6, d = col & 63;
        #pragma unroll
        for (int mi = 0; mi < 4; ++mi) {
            int rowb = m0 + wm + mi * 16 + lg * 4;
            #pragma unroll
            for (int r = 0; r < 4; ++r) {
                int row = rowb + r;
                int bb = row >> 11, s = row & (Sc - 1);
                size_t idx = ((size_t)(bb * NHc + hh) * Sc + s) * HDc + d;
                float v = (acc[mi][ni][r] + bv) * osc;
                if (SPLIT) {
                    HL e = split2(v);
                    outh[idx] = e.h;
                    outl[idx] = e.l;
                } else {
                    outh[idx] = (__bf16)v;
                }
            }
        }
    }
}

// ---------------------------------------------------------------------------
// Flash attention v6 (measured best): K staged via gload_lds with double
// buffer; per-head XCD affinity (flat&31); 32 q-rows/wave; NH2 64-key halves
// per barrier; setprio; defer-max THR=8.
// ---------------------------------------------------------------------------
template<int QKSPLIT, int NH2>
__global__ __launch_bounds__(256) void attn_kernel(
    const __bf16* __restrict__ Qh, const __bf16* __restrict__ Ql,
    const __bf16* __restrict__ Kh, const __bf16* __restrict__ Kl,
    const __bf16* __restrict__ V, __bf16* __restrict__ O)
{
    constexpr int KVB = 64 * NH2;
    __shared__ alignas(16) __bf16 Ksh[2][KVB * 64];
    __shared__ alignas(16) __bf16 Klo[QKSPLIT ? 2 : 1][QKSPLIT ? 64 * 64 : 8];
    __shared__ alignas(16) __bf16 VT[2][NH2][64 * 64];

    const int tid = threadIdx.x;
    const int lane = tid & 63, wave = tid >> 6;
    const int lr = lane & 15, lg = lane >> 4;
    const int flat = blockIdx.x;
    const int hb = flat & 31;            // flat%8 == hb%8: head-XCD affinity
    const int h = hb & 15, b = hb >> 4;
    const int q0 = (flat >> 5) * 128 + wave * 32;

    const size_t headoff = ((size_t)b * NHc + h) * Sc * HDc;
    const __bf16* Qb  = Qh + headoff;
    const __bf16* Kb  = Kh + headoff;
    const __bf16* Klb = QKSPLIT ? (Kl + headoff) : nullptr;
    const __bf16* Vb  = V + headoff;

    const size_t qrowA = (size_t)(q0 + lr) * HDc;
    const size_t qrowB = qrowA + 16 * HDc;
    bf16x8 qfA0 = *(const bf16x8*)(Qb + qrowA + lg * 8);
    bf16x8 qfA1 = *(const bf16x8*)(Qb + qrowA + 32 + lg * 8);
    bf16x8 qfB0 = *(const bf16x8*)(Qb + qrowB + lg * 8);
    bf16x8 qfB1 = *(const bf16x8*)(Qb + qrowB + 32 + lg * 8);
    bf16x8 qlA0, qlA1, qlB0, qlB1;
    if constexpr (QKSPLIT) {
        const __bf16* Qlb = Ql + headoff;
        qlA0 = *(const bf16x8*)(Qlb + qrowA + lg * 8);
        qlA1 = *(const bf16x8*)(Qlb + qrowA + 32 + lg * 8);
        qlB0 = *(const bf16x8*)(Qlb + qrowB + lg * 8);
        qlB1 = *(const bf16x8*)(Qlb + qrowB + 32 + lg * 8);
    }

    const int kp = tid & 31, dblk = tid >> 5;
    const int sp = (kp & 0x11) | ((kp & 0x06) << 1) | ((kp & 0x08) >> 2);

    auto stageK = [&](int kt, int buf) {
        #pragma unroll
        for (int c = 0; c < 2 * NH2; ++c) {
            int li  = c * 256 + tid;
            int row = li >> 3;
            int lcb = ((li & 7) << 4) ^ ((row & 7) << 4);
            size_t goff = (size_t)(kt * KVB + row) * HDc + (lcb >> 1);
            size_t loff = (size_t)(c * 256 + wave * 64) * 16;
            gload_lds16(Kb + goff, (char*)Ksh[buf] + loff);
            if constexpr (QKSPLIT)
                gload_lds16(Klb + goff, (char*)Klo[buf] + loff);
        }
    };
    auto loadV = [&](int kt, int half, bf16x8& va, bf16x8& vb2) {
        const __bf16* vs = Vb + (size_t)(kt * KVB + half * 64 + 2 * kp) * HDc + dblk * 8;
        va  = *(const bf16x8*)vs;
        vb2 = *(const bf16x8*)(vs + HDc);
    };
    auto writeVT = [&](int buf, int half, bf16x8 va, bf16x8 vb2) {
        #pragma unroll
        for (int j = 0; j < 8; ++j) {
            int d = dblk * 8 + j;
            unsigned u = bfbits(va[j]) | (bfbits(vb2[j]) << 16);
            int byte = d * 128 + ((sp * 4) ^ ((d & 7) << 4));
            *(unsigned*)((char*)VT[buf][half] + byte) = u;
        }
    };

    f32x4 oA[4] = {}, oB[4] = {};
    float mA = -1e30f, mB = -1e30f, lsA = 0.f, lsB = 0.f;

    stageK(0, 0);
    {
        bf16x8 va, vb2;
        #pragma unroll
        for (int hf = 0; hf < NH2; ++hf) {
            loadV(0, hf, va, vb2);
            writeVT(0, hf, va, vb2);
        }
    }
    __syncthreads();

    const int NT = Sc / KVB;
    int cur = 0;
    for (int kt = 0; kt < NT; ++kt) {
        const int nb = cur ^ 1;
        const bool pf = (kt + 1 < NT);
        bf16x8 va[NH2], vb2[NH2];
        if (pf) {
            stageK(kt + 1, nb);
            #pragma unroll
            for (int hf = 0; hf < NH2; ++hf) loadV(kt + 1, hf, va[hf], vb2[hf]);
        }

        const char* Kc  = (const char*)Ksh[cur];
        const char* Klc = (const char*)Klo[QKSPLIT ? cur : 0];

        #pragma unroll
        for (int half = 0; half < NH2; ++half) {
            f32x4 sA[4], sB[4];
            __builtin_amdgcn_s_setprio(1);
            #pragma unroll
            for (int kg = 0; kg < 4; ++kg) {
                int ra = half * 64 + kg * 16 + lr;
                int pa0 = (lg * 16) ^ ((ra & 7) << 4);
                int pa1 = (64 + lg * 16) ^ ((ra & 7) << 4);
                bf16x8 kf0 = *(const bf16x8*)(Kc + ra * 128 + pa0);
                bf16x8 kf1 = *(const bf16x8*)(Kc + ra * 128 + pa1);
                f32x4 tA = {}, tB = {};
                tA = mfma16(kf0, qfA0, tA);
                tA = mfma16(kf1, qfA1, tA);
                tB = mfma16(kf0, qfB0, tB);
                tB = mfma16(kf1, qfB1, tB);
                if constexpr (QKSPLIT) {
                    bf16x8 kg0 = *(const bf16x8*)(Klc + ra * 128 + pa0);
                    bf16x8 kg1 = *(const bf16x8*)(Klc + ra * 128 + pa1);
                    tA = mfma16(kg0, qfA0, tA);
                    tA = mfma16(kg1, qfA1, tA);
                    tA = mfma16(kf0, qlA0, tA);
                    tA = mfma16(kf1, qlA1, tA);
                    tB = mfma16(kg0, qfB0, tB);
                    tB = mfma16(kg1, qfB1, tB);
                    tB = mfma16(kf0, qlB0, tB);
                    tB = mfma16(kf1, qlB1, tB);
                }
                sA[kg] = tA;
                sB[kg] = tB;
            }
            __builtin_amdgcn_s_setprio(0);

            float mtA = -1e30f, mtB = -1e30f;
            #pragma unroll
            for (int kg = 0; kg < 4; ++kg)
                #pragma unroll
                for (int r = 0; r < 4; ++r) {
                    mtA = fmaxf(mtA, sA[kg][r]);
                    mtB = fmaxf(mtB, sB[kg][r]);
                }
            mtA = fmaxf(mtA, __shfl_xor(mtA, 16));
            mtA = fmaxf(mtA, __shfl_xor(mtA, 32));
            mtB = fmaxf(mtB, __shfl_xor(mtB, 16));
            mtB = fmaxf(mtB, __shfl_xor(mtB, 32));
            if (!__all(mtA <= mA + 8.f)) {
                float mnew = fmaxf(mA, mtA);
                float fac = EXP2(mA - mnew);
                mA = mnew;
                lsA *= fac;
                #pragma unroll
                for (int r = 0; r < 4; ++r) {
                    float fr = __shfl(fac, (lg << 4) | (lg * 4 + r));
                    #pragma unroll
                    for (int nd = 0; nd < 4; ++nd) oA[nd][r] *= fr;
                }
            }
            if (!__all(mtB <= mB + 8.f)) {
                float mnew = fmaxf(mB, mtB);
                float fac = EXP2(mB - mnew);
                mB = mnew;
                lsB *= fac;
                #pragma unroll
                for (int r = 0; r < 4; ++r) {
                    float fr = __shfl(fac, (lg << 4) | (lg * 4 + r));
                    #pragma unroll
                    for (int nd = 0; nd < 4; ++nd) oB[nd][r] *= fr;
                }
            }
            float psA = 0.f, psB = 0.f;
            #pragma unroll
            for (int kg = 0; kg < 4; ++kg)
                #pragma unroll
                for (int r = 0; r < 4; ++r) {
                    float pA = EXP2(sA[kg][r] - mA);
                    float pB = EXP2(sB[kg][r] - mB);
                    psA += pA;
                    psB += pB;
                    sA[kg][r] = pA;
                    sB[kg][r] = pB;
                }
            psA += __shfl_xor(psA, 16);
            psA += __shfl_xor(psA, 32);
            psB += __shfl_xor(psB, 16);
            psB += __shfl_xor(psB, 32);
            lsA += psA;
            lsB += psB;

            #pragma unroll
            for (int kh2 = 0; kh2 < 2; ++kh2) {
                u32x4 pkA, pkB;
                pkA[0] = packbf(sA[2 * kh2][0],     sA[2 * kh2][1]);
                pkA[1] = packbf(sA[2 * kh2][2],     sA[2 * kh2][3]);
                pkA[2] = packbf(sA[2 * kh2 + 1][0], sA[2 * kh2 + 1][1]);
                pkA[3] = packbf(sA[2 * kh2 + 1][2], sA[2 * kh2 + 1][3]);
                pkB[0] = packbf(sB[2 * kh2][0],     sB[2 * kh2][1]);
                pkB[1] = packbf(sB[2 * kh2][2],     sB[2 * kh2][3]);
                pkB[2] = packbf(sB[2 * kh2 + 1][0], sB[2 * kh2 + 1][1]);
                pkB[3] = packbf(sB[2 * kh2 + 1][2], sB[2 * kh2 + 1][3]);
                bf16x8 pafA = __builtin_bit_cast(bf16x8, pkA);
                bf16x8 pafB = __builtin_bit_cast(bf16x8, pkB);
                __builtin_amdgcn_s_setprio(1);
                #pragma unroll
                for (int nd = 0; nd < 4; ++nd) {
                    int d = nd * 16 + lr;
                    int byte = d * 128 + ((64 * kh2 + 16 * lg) ^ ((d & 7) << 4));
                    bf16x8 vbf = *(const bf16x8*)((const char*)VT[cur][half] + byte);
                    oA[nd] = mfma16(pafA, vbf, oA[nd]);
                    oB[nd] = mfma16(pafB, vbf, oB[nd]);
                }
                __builtin_amdgcn_s_setprio(0);
            }
        }

        if (pf) {
            #pragma unroll
            for (int hf = 0; hf < NH2; ++hf) writeVT(nb, hf, va[hf], vb2[hf]);
        }
        __syncthreads();
        cur = nb;
    }

    #pragma unroll
    for (int r = 0; r < 4; ++r) {
        float lvA = __shfl(lsA, (lg << 4) | (lg * 4 + r));
        float lvB = __shfl(lsB, (lg << 4) | (lg * 4 + r));
        float invA = 1.f / lvA;
        float invB = 1.f / lvB;
        size_t orowA = ((size_t)b * Sc + q0 + lg * 4 + r) * Hc + h * HDc;
        size_t orowB = orowA + (size_t)16 * Hc;
        #pragma unroll
        for (int nd = 0; nd < 4; ++nd) {
            O[orowA + nd * 16 + lr] = (__bf16)(oA[nd][r] * invA);
            O[orowB + nd * 16 + lr] = (__bf16)(oB[nd][r] * invB);
        }
    }
}

// ---------------------------------------------------------------------------
// Fused residual + LayerNorm (2-input): y bf16. f32 master + bf16 copy out.
// ---------------------------------------------------------------------------
__global__ __launch_bounds__(256) void ln_kernel(
    const float* __restrict__ xr, const __bf16* __restrict__ y,
    const float* __restrict__ g, const float* __restrict__ beta,
    float* __restrict__ of, __bf16* __restrict__ oh)
{
    __shared__ float red[2][4];
    const int row = blockIdx.x, t = threadIdx.x;
    const int lane = t & 63, wave = t >> 6;
    const int idx = row * 256 + t;
    float4 a = ((const float4*)xr)[idx];
    bf16x4 cb = ((const bf16x4*)y)[idx];
    float4 v;
    v.x = a.x + (float)cb[0]; v.y = a.y + (float)cb[1];
    v.z = a.z + (float)cb[2]; v.w = a.w + (float)cb[3];
    float s1 = v.x + v.y + v.z + v.w;
    float s2 = v.x * v.x + v.y * v.y + v.z * v.z + v.w * v.w;
    #pragma unroll
    for (int off = 1; off < 64; off <<= 1) {
        s1 += __shfl_xor(s1, off);
        s2 += __shfl_xor(s2, off);
    }
    if (lane == 0) { red[0][wave] = s1; red[1][wave] = s2; }
    __syncthreads();
    s1 = red[0][0] + red[0][1] + red[0][2] + red[0][3];
    s2 = red[1][0] + red[1][1] + red[1][2] + red[1][3];
    const float mu   = s1 * (1.f / Hc);
    const float var  = s2 * (1.f / Hc) - mu * mu;
    const float rstd = rsqrtf(var + EPSc);
    float4 gg = ((const float4*)g)[t];
    float4 bb = ((const float4*)beta)[t];
    float4 r;
    r.x = (v.x - mu) * rstd * gg.x + bb.x;
    r.y = (v.y - mu) * rstd * gg.y + bb.y;
    r.z = (v.z - mu) * rstd * gg.z + bb.z;
    r.w = (v.w - mu) * rstd * gg.w + bb.w;
    ((float4*)of)[idx] = r;
    bf16x4 hh = { (__bf16)r.x, (__bf16)r.y, (__bf16)r.z, (__bf16)r.w };
    ((bf16x4*)oh)[idx] = hh;
}

// ---------------------------------------------------------------------------
// Fused residual + LayerNorm (3-input, for split-K y): v = xr + y1 + y2.
// ---------------------------------------------------------------------------
__global__ __launch_bounds__(256) void ln3_kernel(
    const float* __restrict__ xr, const __bf16* __restrict__ y1,
    const __bf16* __restrict__ y2,
    const float* __restrict__ g, const float* __restrict__ beta,
    float* __restrict__ of, __bf16* __restrict__ oh)
{
    __shared__ float red[2][4];
    const int row = blockIdx.x, t = threadIdx.x;
    const int lane = t & 63, wave = t >> 6;
    const int idx = row * 256 + t;
    float4 a = ((const float4*)xr)[idx];
    bf16x4 c1 = ((const bf16x4*)y1)[idx];
    bf16x4 c2 = ((const bf16x4*)y2)[idx];
    float4 v;
    v.x = a.x + (float)c1[0] + (float)c2[0];
    v.y = a.y + (float)c1[1] + (float)c2[1];
    v.z = a.z + (float)c1[2] + (float)c2[2];
    v.w = a.w + (float)c1[3] + (float)c2[3];
    float s1 = v.x + v.y + v.z + v.w;
    float s2 = v.x * v.x + v.y * v.y + v.z * v.z + v.w * v.w;
    #pragma unroll
    for (int off = 1; off < 64; off <<= 1) {
        s1 += __shfl_xor(s1, off);
        s2 += __shfl_xor(s2, off);
    }
    if (lane == 0) { red[0][wave] = s1; red[1][wave] = s2; }
    __syncthreads();
    s1 = red[0][0] + red[0][1] + red[0][2] + red[0][3];
    s2 = red[1][0] + red[1][1] + red[1][2] + red[1][3];
    const float mu   = s1 * (1.f / Hc);
    const float var  = s2 * (1.f / Hc) - mu * mu;
    const float rstd = rsqrtf(var + EPSc);
    float4 gg = ((const float4*)g)[t];
    float4 bb = ((const float4*)beta)[t];
    float4 r;
    r.x = (v.x - mu) * rstd * gg.x + bb.x;
    r.y = (v.y - mu) * rstd * gg.y + bb.y;
    r.z = (v.z - mu) * rstd * gg.z + bb.z;
    r.w = (v.w - mu) * rstd * gg.w + bb.w;
    ((float4*)of)[idx] = r;
    bf16x4 hh = { (__bf16)r.x, (__bf16)r.y, (__bf16)r.z, (__bf16)r.w };
    ((bf16x4*)oh)[idx] = hh;
}

// ---------------------------------------------------------------------------
extern "C" void kernel_launch(void* const* d_in, const int* in_sizes, int n_in,
                              void* d_out, int out_size, void* d_ws, size_t ws_size,
                              hipStream_t stream)
{
    const float* inp = (const float*)d_in[0];
    const float* pos = (const float*)d_in[1];
    const float* Wq  = (const float*)d_in[2];
    const float* bq  = (const float*)d_in[3];
    const float* Wk  = (const float*)d_in[4];
    const float* bk  = (const float*)d_in[5];
    const float* Wv  = (const float*)d_in[6];
    const float* bv  = (const float*)d_in[7];
    const float* Wo  = (const float*)d_in[8];
    const float* bo  = (const float*)d_in[9];
    const float* lng = (const float*)d_in[10];
    const float* lnb = (const float*)d_in[11];
    const float* W1  = (const float*)d_in[12];
    const float* b1  = (const float*)d_in[13];
    const float* W2  = (const float*)d_in[14];
    const float* b2  = (const float*)d_in[15];

    char* ws = (char*)d_ws;
    const size_t MB = 1u << 20;
    float*  src_f = (float*)(ws);              // 16 MB
    __bf16* src_h = (__bf16*)(ws + 16 * MB);   //  8 MB
    __bf16* src_l = (__bf16*)(ws + 24 * MB);   //  8 MB
    __bf16* qh    = (__bf16*)(ws + 32 * MB);   //  8 MB (head-major)
    __bf16* kh    = (__bf16*)(ws + 40 * MB);   //  8 MB
    __bf16* vv    = (__bf16*)(ws + 48 * MB);   //  8 MB
    __bf16* ctx   = (__bf16*)(ws + 56 * MB);   //  8 MB (row-major)
    __bf16* ql    = (__bf16*)(ws + 64 * MB);   //  8 MB (layer 0 only)
    __bf16* kl    = (__bf16*)(ws + 72 * MB);   //  8 MB
    __bf16* tmpb  = (__bf16*)(ws + 80 * MB);   //  8 MB (bf16 GEMM out; aliased below)
    __bf16* wq0h  = (__bf16*)(ws + 80 * MB);   //  2 MB (layer-0 split weights,
    __bf16* wq0l  = (__bf16*)(ws + 82 * MB);   //        dead before first tmpb use)
    __bf16* wk0h  = (__bf16*)(ws + 84 * MB);
    __bf16* wk0l  = (__bf16*)(ws + 86 * MB);
    __bf16* tmpb2 = (__bf16*)(ws + 88 * MB);   //  8 MB (split-K half 1)
    __bf16* h1    = (__bf16*)(ws + 32 * MB);   // 32 MB alias (qh..ctx, dead by FFN)
    __bf16* wqT   = (__bf16*)(ws + 96 * MB);   // 12 MB each
    __bf16* wkT   = (__bf16*)(ws + 108 * MB);
    __bf16* wvT   = (__bf16*)(ws + 120 * MB);
    __bf16* woT   = (__bf16*)(ws + 132 * MB);
    __bf16* w1T   = (__bf16*)(ws + 144 * MB);  // 48 MB
    __bf16* w2T   = (__bf16*)(ws + 192 * MB);  // 48 MB ; total 240 MB

    const int M = Bc * Sc;  // 4096

    // layers 1-5 only for Wq/Wk (layer 0 uses the split wq0/wk0 path)
    wconv_kernel<<<dim3(16, 16, 5), 256, 0, stream>>>(Wq + (size_t)Hc * Hc,
                                                      wqT + (size_t)Hc * Hc, Hc, Hc);
    wconv_kernel<<<dim3(16, 16, 5), 256, 0, stream>>>(Wk + (size_t)Hc * Hc,
                                                      wkT + (size_t)Hc * Hc, Hc, Hc);
    wconv_kernel<<<dim3(16, 16, 6), 256, 0, stream>>>(Wv, wvT, Hc, Hc);
    wconv_kernel<<<dim3(16, 16, 6), 256, 0, stream>>>(Wo, woT, Hc, Hc);
    wconv_kernel<<<dim3(64, 16, 6), 256, 0, stream>>>(W1, w1T, Hc, PFc);
    wconv_kernel<<<dim3(16, 64, 6), 256, 0, stream>>>(W2, w2T, PFc, Hc);
    wconv2_kernel<<<dim3(16, 16), 256, 0, stream>>>(Wq, wq0h, wq0l, Hc, Hc);
    wconv2_kernel<<<dim3(16, 16), 256, 0, stream>>>(Wk, wk0h, wk0l, Hc, Hc);

    embed_kernel<<<2048, 256, 0, stream>>>(inp, pos, src_f, src_h, src_l);

    for (int l = 0; l < Lc; ++l) {
        const size_t wHH = (size_t)l * Hc * Hc;
        const size_t wH  = (size_t)l * Hc;
        if (l == 0) {
            QKV0S qa = { wq0h, wq0l, wk0h, wk0l, wvT, bq, bk, bv,
                         qh, ql, kh, kl, vv };
            qkv0s_kernel<<<dim3(24, 32), 256, 0, stream>>>(src_h, src_l, qa);
            attn_kernel<1, 1><<<512, 256, 0, stream>>>(qh, ql, kh, kl, vv, ctx);
        } else {
            QKVBT qa = { wqT + wHH, wkT + wHH, wvT + wHH, bq + wH, bk + wH, bv + wH,
                         qh, kh, vv };
            qkv_bt_kernel<<<dim3(24, 32), 256, 0, stream>>>(src_h, qa);
            attn_kernel<0, 2><<<512, 256, 0, stream>>>(qh, nullptr, kh, nullptr, vv, ctx);
        }
        gemm_bt_kernel<64, 1, false><<<dim3(8, 64), 256, 0, stream>>>(
            ctx, woT + wHH, bo + wH, tmpb, M, Hc, Hc);
        ln_kernel<<<M, 256, 0, stream>>>(src_f, tmpb, lng + wH, lnb + wH, src_f, src_h);
        gemm_bt_kernel<128, 1, true><<<dim3(32, 32), 256, 0, stream>>>(
            src_h, w1T + (size_t)l * Hc * PFc, b1 + (size_t)l * PFc, h1, M, PFc, Hc);
        // W2 split-K=2: halves write tmpb (z=0, with bias) and tmpb2 (z=1)
        gemm_btsk_kernel<<<dim3(8, 64, 2), 256, 0, stream>>>(
            h1, w2T + (size_t)l * PFc * Hc, b2 + wH, tmpb, M, Hc, PFc, PFc / 2);
        float* dst = (l == Lc - 1) ? (float*)d_out : src_f;
        ln3_kernel<<<M, 256, 0, stream>>>(src_f, tmpb, tmpb2, lng + wH, lnb + wH, dst, src_h);
    }
}

// Round 19
// 1471.518 us; speedup vs baseline: 1.0386x; 1.0386x over previous
//
#include <hip/hip_runtime.h>
#include <cstdint>

constexpr int Bc = 2, Sc = 2048, Hc = 1024, NHc = 16, HDc = 64, PFc = 4096, Lc = 6;
constexpr float EPSc = 1e-5f;
constexpr float QSC = 0.18033688011112042f;   // 0.125 * log2(e)

using f32x4  = __attribute__((ext_vector_type(4))) float;
using bf16x8 = __attribute__((ext_vector_type(8))) __bf16;
using bf16x4 = __attribute__((ext_vector_type(4))) __bf16;
using u32x4  = __attribute__((ext_vector_type(4))) unsigned;

#if __has_builtin(__builtin_amdgcn_exp2f)
#define EXP2(x) __builtin_amdgcn_exp2f(x)
#else
#define EXP2(x) exp2f(x)
#endif

__device__ __forceinline__ f32x4 mfma16(bf16x8 a, bf16x8 b, f32x4 c) {
    return __builtin_amdgcn_mfma_f32_16x16x32_bf16(a, b, c, 0, 0, 0);
}

__device__ __forceinline__ void gload_lds16(const void* g, void* l) {
    __builtin_amdgcn_global_load_lds(
        (__attribute__((address_space(1))) void*)(uintptr_t)g,
        (__attribute__((address_space(3))) void*)(uint32_t)(uintptr_t)l,
        16, 0, 0);
}

// counted vmcnt wait (T4): leave N newest loads in flight
template<int N> __device__ __forceinline__ void wait_vmcnt() {
    if constexpr (N == 0)      asm volatile("s_waitcnt vmcnt(0)" ::: "memory");
    else if constexpr (N == 4) asm volatile("s_waitcnt vmcnt(4)" ::: "memory");
    else if constexpr (N == 6) asm volatile("s_waitcnt vmcnt(6)" ::: "memory");
    else if constexpr (N == 8) asm volatile("s_waitcnt vmcnt(8)" ::: "memory");
}
__device__ __forceinline__ void wait_lgkm0() {
    asm volatile("s_waitcnt lgkmcnt(0)" ::: "memory");
    __builtin_amdgcn_sched_barrier(0);   // rule 18: fence MFMA hoisting
}

struct HL { __bf16 h, l; };
__device__ __forceinline__ HL split2(float v) {
    HL r;
    r.h = (__bf16)v;
    r.l = (__bf16)(v - (float)r.h);
    return r;
}

__device__ __forceinline__ unsigned bfbits(__bf16 x) {
    return (unsigned)__builtin_bit_cast(unsigned short, x);
}
__device__ __forceinline__ unsigned packbf(float a, float b) {
    return bfbits((__bf16)a) | (bfbits((__bf16)b) << 16);
}

// XCD-aware bijective block swizzle (requires nwg % 8 == 0)
__device__ __forceinline__ int xcd_swz(int bid, int nwg) {
    return (bid & 7) * (nwg >> 3) + (bid >> 3);
}

// ---------------------------------------------------------------------------
// Weight convert: f32 [K][N] -> bf16 [N][K], 64x64 tiles via LDS.
// ---------------------------------------------------------------------------
__global__ __launch_bounds__(256) void wconv_kernel(
    const float* __restrict__ in, __bf16* __restrict__ out, int K, int N)
{
    __shared__ float tile[64][65];
    const int t = threadIdx.x;
    const size_t lstride = (size_t)K * N;
    const float* ip = in + (size_t)blockIdx.z * lstride;
    __bf16* op = out + (size_t)blockIdx.z * lstride;
    const int n0 = blockIdx.x * 64, k0 = blockIdx.y * 64;
    #pragma unroll
    for (int c = 0; c < 4; ++c) {
        int idx = c * 256 + t;
        int row = idx >> 4;
        int c4  = idx & 15;
        float4 v = *(const float4*)(ip + (size_t)(k0 + row) * N + n0 + c4 * 4);
        tile[row][c4 * 4 + 0] = v.x; tile[row][c4 * 4 + 1] = v.y;
        tile[row][c4 * 4 + 2] = v.z; tile[row][c4 * 4 + 3] = v.w;
    }
    __syncthreads();
    #pragma unroll
    for (int c = 0; c < 4; ++c) {
        int idx = c * 256 + t;
        int n  = idx >> 4;
        int k4 = idx & 15;
        bf16x4 hh = { (__bf16)tile[k4 * 4 + 0][n], (__bf16)tile[k4 * 4 + 1][n],
                      (__bf16)tile[k4 * 4 + 2][n], (__bf16)tile[k4 * 4 + 3][n] };
        *(bf16x4*)(op + (size_t)(n0 + n) * K + k0 + k4 * 4) = hh;
    }
}

// ---------------------------------------------------------------------------
// Weight convert split: f32 [K][N] -> bf16 hi [N][K] + lo [N][K] (layer 0 Q/K)
// ---------------------------------------------------------------------------
__global__ __launch_bounds__(256) void wconv2_kernel(
    const float* __restrict__ in, __bf16* __restrict__ outh,
    __bf16* __restrict__ outl, int K, int N)
{
    __shared__ float tile[64][65];
    const int t = threadIdx.x;
    const int n0 = blockIdx.x * 64, k0 = blockIdx.y * 64;
    #pragma unroll
    for (int c = 0; c < 4; ++c) {
        int idx = c * 256 + t;
        int row = idx >> 4;
        int c4  = idx & 15;
        float4 v = *(const float4*)(in + (size_t)(k0 + row) * N + n0 + c4 * 4);
        tile[row][c4 * 4 + 0] = v.x; tile[row][c4 * 4 + 1] = v.y;
        tile[row][c4 * 4 + 2] = v.z; tile[row][c4 * 4 + 3] = v.w;
    }
    __syncthreads();
    #pragma unroll
    for (int c = 0; c < 4; ++c) {
        int idx = c * 256 + t;
        int n  = idx >> 4;
        int k4 = idx & 15;
        HL e0 = split2(tile[k4 * 4 + 0][n]);
        HL e1 = split2(tile[k4 * 4 + 1][n]);
        HL e2 = split2(tile[k4 * 4 + 2][n]);
        HL e3 = split2(tile[k4 * 4 + 3][n]);
        bf16x4 hh = { e0.h, e1.h, e2.h, e3.h };
        bf16x4 ll = { e0.l, e1.l, e2.l, e3.l };
        *(bf16x4*)(outh + (size_t)(n0 + n) * K + k0 + k4 * 4) = hh;
        *(bf16x4*)(outl + (size_t)(n0 + n) * K + k0 + k4 * 4) = ll;
    }
}

// ---------------------------------------------------------------------------
// Embed: src = in*32 + pos ; f32 master + split bf16
// ---------------------------------------------------------------------------
__global__ __launch_bounds__(256) void embed_kernel(
    const float* __restrict__ in, const float* __restrict__ pos,
    float* __restrict__ sf, __bf16* __restrict__ sh, __bf16* __restrict__ sl)
{
    const int n4 = (Bc * Sc * Hc) / 4;
    const int pmask = (Sc * Hc / 4) - 1;
    for (int i = blockIdx.x * 256 + threadIdx.x; i < n4; i += gridDim.x * 256) {
        float4 a = ((const float4*)in)[i];
        float4 p = ((const float4*)pos)[i & pmask];
        float4 r;
        r.x = a.x * 32.f + p.x; r.y = a.y * 32.f + p.y;
        r.z = a.z * 32.f + p.z; r.w = a.w * 32.f + p.w;
        ((float4*)sf)[i] = r;
        HL e0 = split2(r.x), e1 = split2(r.y), e2 = split2(r.z), e3 = split2(r.w);
        bf16x4 hh = { e0.h, e1.h, e2.h, e3.h };
        bf16x4 ll = { e0.l, e1.l, e2.l, e3.l };
        ((bf16x4*)sh)[i] = hh;
        ((bf16x4*)sl)[i] = ll;
    }
}

// ---------------------------------------------------------------------------
// GEMM on pre-transposed bf16 weights. BM x 128 tile, BK=64, 4 waves.
// T4 counted-vmcnt pipeline + XCD swizzle + setprio. OUTMODE: 0=f32, 1=bf16.
// ---------------------------------------------------------------------------
template<int BM, int OUTMODE, bool RELU>
__global__ __launch_bounds__(256) void gemm_bt_kernel(
    const __bf16* __restrict__ A, const __bf16* __restrict__ Wt,
    const float* __restrict__ bias, void* __restrict__ out,
    int M, int N, int K)
{
    constexpr int MI = BM / 32;
    constexpr int LPT = BM / 32 + 4;   // gloads per thread per stage
    __shared__ alignas(16) __bf16 Alds[2][BM * 64];
    __shared__ alignas(16) __bf16 Blds[2][128 * 64];

    const int tid = threadIdx.x, lane = tid & 63, wave = tid >> 6;
    const int lr = lane & 15, lg = lane >> 4;
    const int nbx = gridDim.x;
    const int swz = xcd_swz(blockIdx.y * nbx + blockIdx.x, nbx * gridDim.y);
    const int m0 = (swz / nbx) * BM, n0 = (swz % nbx) * 128;
    const int wm = (wave >> 1) * (BM / 2), wn = (wave & 1) * 64;

    f32x4 acc[MI][4] = {};

    auto stage = [&](int k0, int buf) {
        #pragma unroll
        for (int c = 0; c < BM / 32; ++c) {
            int li = c * 256 + tid;
            int row = li >> 3;
            int lcb = ((li & 7) << 4) ^ ((row & 7) << 4);
            gload_lds16(A + (size_t)(m0 + row) * K + k0 + (lcb >> 1),
                        (char*)Alds[buf] + (size_t)(c * 256 + wave * 64) * 16);
        }
        #pragma unroll
        for (int c = 0; c < 4; ++c) {
            int li = c * 256 + tid;
            int row = li >> 3;
            int lcb = ((li & 7) << 4) ^ ((row & 7) << 4);
            gload_lds16(Wt + (size_t)(n0 + row) * K + k0 + (lcb >> 1),
                        (char*)Blds[buf] + (size_t)(c * 256 + wave * 64) * 16);
        }
    };

    stage(0, 0);
    if (K > 64) stage(64, 1);

    for (int k0 = 0; k0 < K; k0 += 64) {
        const int cur = (k0 >> 6) & 1;
        if (k0 + 64 < K) wait_vmcnt<LPT>();
        else             wait_vmcnt<0>();
        __builtin_amdgcn_s_barrier();

        bf16x8 af[2][MI], bfr[2][4];
        #pragma unroll
        for (int ks = 0; ks < 2; ++ks) {
            #pragma unroll
            for (int i = 0; i < MI; ++i) {
                int ra = wm + i * 16 + lr;
                int pa = (ks * 64 + lg * 16) ^ ((ra & 7) << 4);
                af[ks][i] = *(const bf16x8*)((const char*)Alds[cur] + ra * 128 + pa);
            }
            #pragma unroll
            for (int i = 0; i < 4; ++i) {
                int rb = wn + i * 16 + lr;
                int pb = (ks * 64 + lg * 16) ^ ((rb & 7) << 4);
                bfr[ks][i] = *(const bf16x8*)((const char*)Blds[cur] + rb * 128 + pb);
            }
        }
        wait_lgkm0();
        __builtin_amdgcn_s_barrier();
        if (k0 + 128 < K) stage(k0 + 128, cur);

        __builtin_amdgcn_s_setprio(1);
        #pragma unroll
        for (int ks = 0; ks < 2; ++ks)
            #pragma unroll
            for (int mi = 0; mi < MI; ++mi)
                #pragma unroll
                for (int ni = 0; ni < 4; ++ni)
                    acc[mi][ni] = mfma16(af[ks][mi], bfr[ks][ni], acc[mi][ni]);
        __builtin_amdgcn_s_setprio(0);
    }

    #pragma unroll
    for (int ni = 0; ni < 4; ++ni) {
        int col = n0 + wn + ni * 16 + lr;
        float bv = bias[col];
        #pragma unroll
        for (int mi = 0; mi < MI; ++mi) {
            int rowb = m0 + wm + mi * 16 + lg * 4;
            #pragma unroll
            for (int r = 0; r < 4; ++r) {
                float v = acc[mi][ni][r] + bv;
                if (RELU) v = fmaxf(v, 0.f);
                size_t idx = (size_t)(rowb + r) * N + col;
                if constexpr (OUTMODE == 0) ((float*)out)[idx] = v;
                else                        ((__bf16*)out)[idx] = (__bf16)v;
            }
        }
    }
}

// ---------------------------------------------------------------------------
// 8-phase 256x256 GEMM (T3+T4 full form). 8 waves (2M x 4N), BK=64, LDS 128KB
// as 2 K-tile buffers x {A,B} x 2 halves of 128x64. Per K-tile: 4 phases, one
// C-quadrant (16 MFMA) each; ds_reads 12/4/8/0; stages: C0 -> (t+1) B-halves,
// C3 -> (t+2) A-halves. vmcnt(4)+barrier once per K-tile at C0 guarantees
// tile t fully landed (leaves the newest A-stage's 4 loads in flight).
// Ledger (proof): reads of buf(t) A complete by C2(t) end-barrier -> C3(t)
// stage of (t+2,A) into buf(t) safe. Reads of buf(t+1)=buf(t-1) B completed
// at C1(t-1) -> C0(t) stage of (t+1,B) safe. At C0(t), outstanding stages
// newest-first: C3(t-1)=(t+1,A) 4 loads; older = (t,B),(t,A) -> vmcnt(4)
// forces (t,*) landed. Final tile: vmcnt(0).
// ---------------------------------------------------------------------------
template<int OUTMODE, bool RELU>
__global__ __launch_bounds__(512, 2) void gemm8p_kernel(
    const __bf16* __restrict__ A, const __bf16* __restrict__ Wt,
    const float* __restrict__ bias, void* __restrict__ out,
    int M, int N, int K)
{
    __shared__ alignas(16) __bf16 AL[2][2][128 * 64];   // [buf][half]
    __shared__ alignas(16) __bf16 BL[2][2][128 * 64];

    const int tid = threadIdx.x, lane = tid & 63, wave = tid >> 6;
    const int lr = lane & 15, lg = lane >> 4;
    const int wr = wave >> 2, wc = wave & 3;            // 2M x 4N wave grid
    const int nbx = gridDim.x;
    const int swz = xcd_swz(blockIdx.y * nbx + blockIdx.x, nbx * gridDim.y);
    const int m0 = (swz / nbx) * 256, n0 = (swz % nbx) * 256;
    const int NT = K >> 6;
    const int brow = (wc & 1) * 64;                     // B row base in its half

    f32x4 acc[8][4] = {};

    auto stageA = [&](int t, int half) {                // 2 gloads/thread
        #pragma unroll
        for (int c = 0; c < 2; ++c) {
            int li = c * 512 + tid;
            int row = li >> 3;
            int lcb = ((li & 7) << 4) ^ ((row & 7) << 4);
            gload_lds16(A + (size_t)(m0 + half * 128 + row) * K + t * 64 + (lcb >> 1),
                        (char*)AL[t & 1][half] + (size_t)(c * 512 + wave * 64) * 16);
        }
    };
    auto stageB = [&](int t, int half) {
        #pragma unroll
        for (int c = 0; c < 2; ++c) {
            int li = c * 512 + tid;
            int row = li >> 3;
            int lcb = ((li & 7) << 4) ^ ((row & 7) << 4);
            gload_lds16(Wt + (size_t)(n0 + half * 128 + row) * K + t * 64 + (lcb >> 1),
                        (char*)BL[t & 1][half] + (size_t)(c * 512 + wave * 64) * 16);
        }
    };

    // prologue: K-tile 0 complete + K-tile 1 A-halves
    stageA(0, 0); stageA(0, 1); stageB(0, 0); stageB(0, 1);
    if (NT > 1) { stageA(1, 0); stageA(1, 1); }

    bf16x8 af[2][4], b0[2][2], b1[2][2];

    for (int t = 0; t < NT; ++t) {
        const char* Ah = (const char*)AL[t & 1][wr];
        const char* Bh = (const char*)BL[t & 1][wc >> 1];

        // ---- C0: data-ready sync; read A-quad0 + B-quad0; stage (t+1,B) ----
        if (t == NT - 1) wait_vmcnt<0>(); else wait_vmcnt<4>();
        __builtin_amdgcn_s_barrier();
        #pragma unroll
        for (int ks = 0; ks < 2; ++ks) {
            #pragma unroll
            for (int i = 0; i < 4; ++i) {
                int row = i * 16 + lr;
                af[ks][i] = *(const bf16x8*)(Ah + row * 128 +
                            ((ks * 64 + lg * 16) ^ ((row & 7) << 4)));
            }
            #pragma unroll
            for (int j = 0; j < 2; ++j) {
                int row = brow + j * 16 + lr;
                b0[ks][j] = *(const bf16x8*)(Bh + row * 128 +
                            ((ks * 64 + lg * 16) ^ ((row & 7) << 4)));
            }
        }
        if (t + 1 < NT) { stageB(t + 1, 0); stageB(t + 1, 1); }
        __builtin_amdgcn_s_barrier();
        wait_lgkm0();
        __builtin_amdgcn_s_setprio(1);
        #pragma unroll
        for (int ks = 0; ks < 2; ++ks)
            #pragma unroll
            for (int mi = 0; mi < 4; ++mi)
                #pragma unroll
                for (int j = 0; j < 2; ++j)
                    acc[mi][j] = mfma16(af[ks][mi], b0[ks][j], acc[mi][j]);
        __builtin_amdgcn_s_setprio(0);
        __builtin_amdgcn_s_barrier();

        // ---- C1: read B-quad1; MFMA m0-3 x n2-3 ----
        #pragma unroll
        for (int ks = 0; ks < 2; ++ks)
            #pragma unroll
            for (int j = 0; j < 2; ++j) {
                int row = brow + (2 + j) * 16 + lr;
                b1[ks][j] = *(const bf16x8*)(Bh + row * 128 +
                            ((ks * 64 + lg * 16) ^ ((row & 7) << 4)));
            }
        __builtin_amdgcn_s_barrier();
        wait_lgkm0();
        __builtin_amdgcn_s_setprio(1);
        #pragma unroll
        for (int ks = 0; ks < 2; ++ks)
            #pragma unroll
            for (int mi = 0; mi < 4; ++mi)
                #pragma unroll
                for (int j = 0; j < 2; ++j)
                    acc[mi][2 + j] = mfma16(af[ks][mi], b1[ks][j], acc[mi][2 + j]);
        __builtin_amdgcn_s_setprio(0);
        __builtin_amdgcn_s_barrier();

        // ---- C2: read A-quad1; MFMA m4-7 x n2-3 ----
        #pragma unroll
        for (int ks = 0; ks < 2; ++ks)
            #pragma unroll
            for (int i = 0; i < 4; ++i) {
                int row = (4 + i) * 16 + lr;
                af[ks][i] = *(const bf16x8*)(Ah + row * 128 +
                            ((ks * 64 + lg * 16) ^ ((row & 7) << 4)));
            }
        __builtin_amdgcn_s_barrier();
        wait_lgkm0();
        __builtin_amdgcn_s_setprio(1);
        #pragma unroll
        for (int ks = 0; ks < 2; ++ks)
            #pragma unroll
            for (int mi = 0; mi < 4; ++mi)
                #pragma unroll
                for (int j = 0; j < 2; ++j)
                    acc[4 + mi][2 + j] = mfma16(af[ks][mi], b1[ks][j], acc[4 + mi][2 + j]);
        __builtin_amdgcn_s_setprio(0);
        __builtin_amdgcn_s_barrier();

        // ---- C3: stage (t+2,A); MFMA m4-7 x n0-1 ----
        if (t + 2 < NT) { stageA(t + 2, 0); stageA(t + 2, 1); }
        __builtin_amdgcn_s_barrier();
        __builtin_amdgcn_s_setprio(1);
        #pragma unroll
        for (int ks = 0; ks < 2; ++ks)
            #pragma unroll
            for (int mi = 0; mi < 4; ++mi)
                #pragma unroll
                for (int j = 0; j < 2; ++j)
                    acc[4 + mi][j] = mfma16(af[ks][mi], b0[ks][j], acc[4 + mi][j]);
        __builtin_amdgcn_s_setprio(0);
        __builtin_amdgcn_s_barrier();
    }

    // ---- epilogue ----
    #pragma unroll
    for (int ni = 0; ni < 4; ++ni) {
        int col = n0 + wc * 64 + ni * 16 + lr;
        float bv = bias[col];
        #pragma unroll
        for (int mi = 0; mi < 8; ++mi) {
            int rowb = m0 + wr * 128 + mi * 16 + lg * 4;
            #pragma unroll
            for (int r = 0; r < 4; ++r) {
                float v = acc[mi][ni][r] + bv;
                if (RELU) v = fmaxf(v, 0.f);
                size_t idx = (size_t)(rowb + r) * N + col;
                if constexpr (OUTMODE == 0) ((float*)out)[idx] = v;
                else                        ((__bf16*)out)[idx] = (__bf16)v;
            }
        }
    }
}

// ---------------------------------------------------------------------------
// Fused QKV on pre-transposed bf16 weights (layers >= 1). Head-major out.
// T4 counted-vmcnt pipeline. q pre-scaled by QSC.
// ---------------------------------------------------------------------------
struct QKVBT {
    const __bf16 *wq, *wk, *wv;
    const float *bq, *bk, *bv;
    __bf16 *q, *k, *v;
};

__global__ __launch_bounds__(256) void qkv_bt_kernel(
    const __bf16* __restrict__ A, QKVBT a)
{
    constexpr int N = Hc, K = Hc;
    constexpr int LPT = 8;
    __shared__ alignas(16) __bf16 Alds[2][128 * 64];
    __shared__ alignas(16) __bf16 Blds[2][128 * 64];

    const int tid = threadIdx.x, lane = tid & 63, wave = tid >> 6;
    const int lr = lane & 15, lg = lane >> 4;
    const int nbx = gridDim.x;
    const int swz = xcd_swz(blockIdx.y * nbx + blockIdx.x, nbx * gridDim.y);
    const int gx = swz % nbx;
    const int widx = gx >> 3;
    const int n0 = (gx & 7) * 128;
    const int m0 = (swz / nbx) * 128;
    const int wm = (wave >> 1) * 64, wn = (wave & 1) * 64;

    const __bf16* Wt  = (widx == 0) ? a.wq : (widx == 1) ? a.wk : a.wv;
    const float* bias = (widx == 0) ? a.bq : (widx == 1) ? a.bk : a.bv;

    f32x4 acc[4][4] = {};

    auto stage = [&](int k0, int buf) {
        #pragma unroll
        for (int c = 0; c < 4; ++c) {
            int li = c * 256 + tid;
            int row = li >> 3;
            int lcb = ((li & 7) << 4) ^ ((row & 7) << 4);
            gload_lds16(A + (size_t)(m0 + row) * K + k0 + (lcb >> 1),
                        (char*)Alds[buf] + (size_t)(c * 256 + wave * 64) * 16);
            gload_lds16(Wt + (size_t)(n0 + row) * K + k0 + (lcb >> 1),
                        (char*)Blds[buf] + (size_t)(c * 256 + wave * 64) * 16);
        }
    };

    stage(0, 0);
    stage(64, 1);

    for (int k0 = 0; k0 < K; k0 += 64) {
        const int cur = (k0 >> 6) & 1;
        if (k0 + 64 < K) wait_vmcnt<LPT>();
        else             wait_vmcnt<0>();
        __builtin_amdgcn_s_barrier();

        bf16x8 af[2][4], bfr[2][4];
        #pragma unroll
        for (int ks = 0; ks < 2; ++ks) {
            #pragma unroll
            for (int i = 0; i < 4; ++i) {
                int ra = wm + i * 16 + lr;
                int pa = (ks * 64 + lg * 16) ^ ((ra & 7) << 4);
                af[ks][i] = *(const bf16x8*)((const char*)Alds[cur] + ra * 128 + pa);
                int rb = wn + i * 16 + lr;
                int pb = (ks * 64 + lg * 16) ^ ((rb & 7) << 4);
                bfr[ks][i] = *(const bf16x8*)((const char*)Blds[cur] + rb * 128 + pb);
            }
        }
        wait_lgkm0();
        __builtin_amdgcn_s_barrier();
        if (k0 + 128 < K) stage(k0 + 128, cur);

        __builtin_amdgcn_s_setprio(1);
        #pragma unroll
        for (int ks = 0; ks < 2; ++ks)
            #pragma unroll
            for (int mi = 0; mi < 4; ++mi)
                #pragma unroll
                for (int ni = 0; ni < 4; ++ni)
                    acc[mi][ni] = mfma16(af[ks][mi], bfr[ks][ni], acc[mi][ni]);
        __builtin_amdgcn_s_setprio(0);
    }

    __bf16* outp = (widx == 0) ? a.q : (widx == 1) ? a.k : a.v;
    const float osc = (widx == 0) ? QSC : 1.f;
    #pragma unroll
    for (int ni = 0; ni < 4; ++ni) {
        int col = n0 + wn + ni * 16 + lr;
        float bv = bias[col];
        int hh = col >> 6, d = col & 63;
        #pragma unroll
        for (int mi = 0; mi < 4; ++mi) {
            int rowb = m0 + wm + mi * 16 + lg * 4;
            #pragma unroll
            for (int r = 0; r < 4; ++r) {
                int row = rowb + r;
                int bb = row >> 11, s = row & (Sc - 1);
                outp[((size_t)(bb * NHc + hh) * Sc + s) * HDc + d] =
                    (__bf16)((acc[mi][ni][r] + bv) * osc);
            }
        }
    }
}

// ---------------------------------------------------------------------------
// Layer-0 QKV, all-gload version. Q,K: split x split (3 MFMA). V plain.
// ---------------------------------------------------------------------------
struct QKV0S {
    const __bf16 *wqh, *wql, *wkh, *wkl, *wv;
    const float *bq, *bk, *bv;
    __bf16 *qh, *ql, *kh, *kl, *vv;
};

__global__ __launch_bounds__(256) void qkv0s_kernel(
    const __bf16* __restrict__ Ahi, const __bf16* __restrict__ Alo, QKV0S a)
{
    constexpr int N = Hc, K = Hc;
    __shared__ alignas(16) __bf16 AldsH[128 * 64];
    __shared__ alignas(16) __bf16 AldsL[128 * 64];
    __shared__ alignas(16) __bf16 BldsH[128 * 64];
    __shared__ alignas(16) __bf16 BldsL[128 * 64];

    const int tid = threadIdx.x, lane = tid & 63, wave = tid >> 6;
    const int lr = lane & 15, lg = lane >> 4;
    const int nbx = gridDim.x;
    const int swz = xcd_swz(blockIdx.y * nbx + blockIdx.x, nbx * gridDim.y);
    const int gx = swz % nbx;
    const int widx = gx >> 3;
    const int n0 = (gx & 7) * 128;
    const int m0 = (swz / nbx) * 128;
    const int wm = (wave >> 1) * 64, wn = (wave & 1) * 64;
    const bool SPLIT = (widx < 2);

    const __bf16* Bh = (widx == 0) ? a.wqh : (widx == 1) ? a.wkh : a.wv;
    const __bf16* Bl = (widx == 0) ? a.wql : a.wkl;
    const float* bias = (widx == 0) ? a.bq : (widx == 1) ? a.bk : a.bv;

    f32x4 acc[4][4] = {};

    for (int k0 = 0; k0 < K; k0 += 64) {
        #pragma unroll
        for (int c = 0; c < 4; ++c) {
            int li = c * 256 + tid;
            int row = li >> 3;
            int lcb = ((li & 7) << 4) ^ ((row & 7) << 4);
            size_t aoff = (size_t)(m0 + row) * K + k0 + (lcb >> 1);
            size_t boff = (size_t)(n0 + row) * K + k0 + (lcb >> 1);
            size_t loff = (size_t)(c * 256 + wave * 64) * 16;
            gload_lds16(Ahi + aoff, (char*)AldsH + loff);
            gload_lds16(Bh + boff, (char*)BldsH + loff);
            if (SPLIT) {
                gload_lds16(Alo + aoff, (char*)AldsL + loff);
                gload_lds16(Bl + boff, (char*)BldsL + loff);
            }
        }
        __syncthreads();

        bf16x8 ah[2][4], al[2][4], bh[2][4], bl[2][4];
        #pragma unroll
        for (int ks = 0; ks < 2; ++ks) {
            #pragma unroll
            for (int i = 0; i < 4; ++i) {
                int ra = wm + i * 16 + lr;
                int pa = (ks * 64 + lg * 16) ^ ((ra & 7) << 4);
                ah[ks][i] = *(const bf16x8*)((const char*)AldsH + ra * 128 + pa);
                int rb = wn + i * 16 + lr;
                int pb = (ks * 64 + lg * 16) ^ ((rb & 7) << 4);
                bh[ks][i] = *(const bf16x8*)((const char*)BldsH + rb * 128 + pb);
                if (SPLIT) {
                    al[ks][i] = *(const bf16x8*)((const char*)AldsL + ra * 128 + pa);
                    bl[ks][i] = *(const bf16x8*)((const char*)BldsL + rb * 128 + pb);
                }
            }
        }
        #pragma unroll
        for (int ks = 0; ks < 2; ++ks)
            #pragma unroll
            for (int mi = 0; mi < 4; ++mi)
                #pragma unroll
                for (int ni = 0; ni < 4; ++ni) {
                    acc[mi][ni] = mfma16(ah[ks][mi], bh[ks][ni], acc[mi][ni]);
                    if (SPLIT) {
                        acc[mi][ni] = mfma16(al[ks][mi], bh[ks][ni], acc[mi][ni]);
                        acc[mi][ni] = mfma16(ah[ks][mi], bl[ks][ni], acc[mi][ni]);
                    }
                }
        __syncthreads();
    }

    __bf16* outh = (widx == 0) ? a.qh : (widx == 1) ? a.kh : a.vv;
    __bf16* outl = (widx == 0) ? a.ql : a.kl;
    const float osc = (widx == 0) ? QSC : 1.f;
    #pragma unroll
    for (int ni = 0; ni < 4; ++ni) {
        int col = n0 + wn + ni * 16 + lr;
        float bv = bias[col];
        int hh = col >> 6, d = col & 63;
        #pragma unroll
        for (int mi = 0; mi < 4; ++mi) {
            int rowb = m0 + wm + mi * 16 + lg * 4;
            #pragma unroll
            for (int r = 0; r < 4; ++r) {
                int row = rowb + r;
                int bb = row >> 11, s = row & (Sc - 1);
                size_t idx = ((size_t)(bb * NHc + hh) * Sc + s) * HDc + d;
                float v = (acc[mi][ni][r] + bv) * osc;
                if (SPLIT) {
                    HL e = split2(v);
                    outh[idx] = e.h;
                    outl[idx] = e.l;
                } else {
                    outh[idx] = (__bf16)v;
                }
            }
        }
    }
}

// ---------------------------------------------------------------------------
// Flash attention v6 (measured best): K staged via gload_lds with double
// buffer; per-head XCD affinity (flat&31); 32 q-rows/wave; NH2 64-key halves
// per barrier; setprio; defer-max THR=8.
// ---------------------------------------------------------------------------
template<int QKSPLIT, int NH2>
__global__ __launch_bounds__(256) void attn_kernel(
    const __bf16* __restrict__ Qh, const __bf16* __restrict__ Ql,
    const __bf16* __restrict__ Kh, const __bf16* __restrict__ Kl,
    const __bf16* __restrict__ V, __bf16* __restrict__ O)
{
    constexpr int KVB = 64 * NH2;
    __shared__ alignas(16) __bf16 Ksh[2][KVB * 64];
    __shared__ alignas(16) __bf16 Klo[QKSPLIT ? 2 : 1][QKSPLIT ? 64 * 64 : 8];
    __shared__ alignas(16) __bf16 VT[2][NH2][64 * 64];

    const int tid = threadIdx.x;
    const int lane = tid & 63, wave = tid >> 6;
    const int lr = lane & 15, lg = lane >> 4;
    const int flat = blockIdx.x;
    const int hb = flat & 31;            // flat%8 == hb%8: head-XCD affinity
    const int h = hb & 15, b = hb >> 4;
    const int q0 = (flat >> 5) * 128 + wave * 32;

    const size_t headoff = ((size_t)b * NHc + h) * Sc * HDc;
    const __bf16* Qb  = Qh + headoff;
    const __bf16* Kb  = Kh + headoff;
    const __bf16* Klb = QKSPLIT ? (Kl + headoff) : nullptr;
    const __bf16* Vb  = V + headoff;

    const size_t qrowA = (size_t)(q0 + lr) * HDc;
    const size_t qrowB = qrowA + 16 * HDc;
    bf16x8 qfA0 = *(const bf16x8*)(Qb + qrowA + lg * 8);
    bf16x8 qfA1 = *(const bf16x8*)(Qb + qrowA + 32 + lg * 8);
    bf16x8 qfB0 = *(const bf16x8*)(Qb + qrowB + lg * 8);
    bf16x8 qfB1 = *(const bf16x8*)(Qb + qrowB + 32 + lg * 8);
    bf16x8 qlA0, qlA1, qlB0, qlB1;
    if constexpr (QKSPLIT) {
        const __bf16* Qlb = Ql + headoff;
        qlA0 = *(const bf16x8*)(Qlb + qrowA + lg * 8);
        qlA1 = *(const bf16x8*)(Qlb + qrowA + 32 + lg * 8);
        qlB0 = *(const bf16x8*)(Qlb + qrowB + lg * 8);
        qlB1 = *(const bf16x8*)(Qlb + qrowB + 32 + lg * 8);
    }

    const int kp = tid & 31, dblk = tid >> 5;
    const int sp = (kp & 0x11) | ((kp & 0x06) << 1) | ((kp & 0x08) >> 2);

    auto stageK = [&](int kt, int buf) {
        #pragma unroll
        for (int c = 0; c < 2 * NH2; ++c) {
            int li  = c * 256 + tid;
            int row = li >> 3;
            int lcb = ((li & 7) << 4) ^ ((row & 7) << 4);
            size_t goff = (size_t)(kt * KVB + row) * HDc + (lcb >> 1);
            size_t loff = (size_t)(c * 256 + wave * 64) * 16;
            gload_lds16(Kb + goff, (char*)Ksh[buf] + loff);
            if constexpr (QKSPLIT)
                gload_lds16(Klb + goff, (char*)Klo[buf] + loff);
        }
    };
    auto loadV = [&](int kt, int half, bf16x8& va, bf16x8& vb2) {
        const __bf16* vs = Vb + (size_t)(kt * KVB + half * 64 + 2 * kp) * HDc + dblk * 8;
        va  = *(const bf16x8*)vs;
        vb2 = *(const bf16x8*)(vs + HDc);
    };
    auto writeVT = [&](int buf, int half, bf16x8 va, bf16x8 vb2) {
        #pragma unroll
        for (int j = 0; j < 8; ++j) {
            int d = dblk * 8 + j;
            unsigned u = bfbits(va[j]) | (bfbits(vb2[j]) << 16);
            int byte = d * 128 + ((sp * 4) ^ ((d & 7) << 4));
            *(unsigned*)((char*)VT[buf][half] + byte) = u;
        }
    };

    f32x4 oA[4] = {}, oB[4] = {};
    float mA = -1e30f, mB = -1e30f, lsA = 0.f, lsB = 0.f;

    stageK(0, 0);
    {
        bf16x8 va, vb2;
        #pragma unroll
        for (int hf = 0; hf < NH2; ++hf) {
            loadV(0, hf, va, vb2);
            writeVT(0, hf, va, vb2);
        }
    }
    __syncthreads();

    const int NT = Sc / KVB;
    int cur = 0;
    for (int kt = 0; kt < NT; ++kt) {
        const int nb = cur ^ 1;
        const bool pf = (kt + 1 < NT);
        bf16x8 va[NH2], vb2[NH2];
        if (pf) {
            stageK(kt + 1, nb);
            #pragma unroll
            for (int hf = 0; hf < NH2; ++hf) loadV(kt + 1, hf, va[hf], vb2[hf]);
        }

        const char* Kc  = (const char*)Ksh[cur];
        const char* Klc = (const char*)Klo[QKSPLIT ? cur : 0];

        #pragma unroll
        for (int half = 0; half < NH2; ++half) {
            f32x4 sA[4], sB[4];
            __builtin_amdgcn_s_setprio(1);
            #pragma unroll
            for (int kg = 0; kg < 4; ++kg) {
                int ra = half * 64 + kg * 16 + lr;
                int pa0 = (lg * 16) ^ ((ra & 7) << 4);
                int pa1 = (64 + lg * 16) ^ ((ra & 7) << 4);
                bf16x8 kf0 = *(const bf16x8*)(Kc + ra * 128 + pa0);
                bf16x8 kf1 = *(const bf16x8*)(Kc + ra * 128 + pa1);
                f32x4 tA = {}, tB = {};
                tA = mfma16(kf0, qfA0, tA);
                tA = mfma16(kf1, qfA1, tA);
                tB = mfma16(kf0, qfB0, tB);
                tB = mfma16(kf1, qfB1, tB);
                if constexpr (QKSPLIT) {
                    bf16x8 kg0 = *(const bf16x8*)(Klc + ra * 128 + pa0);
                    bf16x8 kg1 = *(const bf16x8*)(Klc + ra * 128 + pa1);
                    tA = mfma16(kg0, qfA0, tA);
                    tA = mfma16(kg1, qfA1, tA);
                    tA = mfma16(kf0, qlA0, tA);
                    tA = mfma16(kf1, qlA1, tA);
                    tB = mfma16(kg0, qfB0, tB);
                    tB = mfma16(kg1, qfB1, tB);
                    tB = mfma16(kf0, qlB0, tB);
                    tB = mfma16(kf1, qlB1, tB);
                }
                sA[kg] = tA;
                sB[kg] = tB;
            }
            __builtin_amdgcn_s_setprio(0);

            float mtA = -1e30f, mtB = -1e30f;
            #pragma unroll
            for (int kg = 0; kg < 4; ++kg)
                #pragma unroll
                for (int r = 0; r < 4; ++r) {
                    mtA = fmaxf(mtA, sA[kg][r]);
                    mtB = fmaxf(mtB, sB[kg][r]);
                }
            mtA = fmaxf(mtA, __shfl_xor(mtA, 16));
            mtA = fmaxf(mtA, __shfl_xor(mtA, 32));
            mtB = fmaxf(mtB, __shfl_xor(mtB, 16));
            mtB = fmaxf(mtB, __shfl_xor(mtB, 32));
            if (!__all(mtA <= mA + 8.f)) {
                float mnew = fmaxf(mA, mtA);
                float fac = EXP2(mA - mnew);
                mA = mnew;
                lsA *= fac;
                #pragma unroll
                for (int r = 0; r < 4; ++r) {
                    float fr = __shfl(fac, (lg << 4) | (lg * 4 + r));
                    #pragma unroll
                    for (int nd = 0; nd < 4; ++nd) oA[nd][r] *= fr;
                }
            }
            if (!__all(mtB <= mB + 8.f)) {
                float mnew = fmaxf(mB, mtB);
                float fac = EXP2(mB - mnew);
                mB = mnew;
                lsB *= fac;
                #pragma unroll
                for (int r = 0; r < 4; ++r) {
                    float fr = __shfl(fac, (lg << 4) | (lg * 4 + r));
                    #pragma unroll
                    for (int nd = 0; nd < 4; ++nd) oB[nd][r] *= fr;
                }
            }
            float psA = 0.f, psB = 0.f;
            #pragma unroll
            for (int kg = 0; kg < 4; ++kg)
                #pragma unroll
                for (int r = 0; r < 4; ++r) {
                    float pA = EXP2(sA[kg][r] - mA);
                    float pB = EXP2(sB[kg][r] - mB);
                    psA += pA;
                    psB += pB;
                    sA[kg][r] = pA;
                    sB[kg][r] = pB;
                }
            psA += __shfl_xor(psA, 16);
            psA += __shfl_xor(psA, 32);
            psB += __shfl_xor(psB, 16);
            psB += __shfl_xor(psB, 32);
            lsA += psA;
            lsB += psB;

            #pragma unroll
            for (int kh2 = 0; kh2 < 2; ++kh2) {
                u32x4 pkA, pkB;
                pkA[0] = packbf(sA[2 * kh2][0],     sA[2 * kh2][1]);
                pkA[1] = packbf(sA[2 * kh2][2],     sA[2 * kh2][3]);
                pkA[2] = packbf(sA[2 * kh2 + 1][0], sA[2 * kh2 + 1][1]);
                pkA[3] = packbf(sA[2 * kh2 + 1][2], sA[2 * kh2 + 1][3]);
                pkB[0] = packbf(sB[2 * kh2][0],     sB[2 * kh2][1]);
                pkB[1] = packbf(sB[2 * kh2][2],     sB[2 * kh2][3]);
                pkB[2] = packbf(sB[2 * kh2 + 1][0], sB[2 * kh2 + 1][1]);
                pkB[3] = packbf(sB[2 * kh2 + 1][2], sB[2 * kh2 + 1][3]);
                bf16x8 pafA = __builtin_bit_cast(bf16x8, pkA);
                bf16x8 pafB = __builtin_bit_cast(bf16x8, pkB);
                __builtin_amdgcn_s_setprio(1);
                #pragma unroll
                for (int nd = 0; nd < 4; ++nd) {
                    int d = nd * 16 + lr;
                    int byte = d * 128 + ((64 * kh2 + 16 * lg) ^ ((d & 7) << 4));
                    bf16x8 vbf = *(const bf16x8*)((const char*)VT[cur][half] + byte);
                    oA[nd] = mfma16(pafA, vbf, oA[nd]);
                    oB[nd] = mfma16(pafB, vbf, oB[nd]);
                }
                __builtin_amdgcn_s_setprio(0);
            }
        }

        if (pf) {
            #pragma unroll
            for (int hf = 0; hf < NH2; ++hf) writeVT(nb, hf, va[hf], vb2[hf]);
        }
        __syncthreads();
        cur = nb;
    }

    #pragma unroll
    for (int r = 0; r < 4; ++r) {
        float lvA = __shfl(lsA, (lg << 4) | (lg * 4 + r));
        float lvB = __shfl(lsB, (lg << 4) | (lg * 4 + r));
        float invA = 1.f / lvA;
        float invB = 1.f / lvB;
        size_t orowA = ((size_t)b * Sc + q0 + lg * 4 + r) * Hc + h * HDc;
        size_t orowB = orowA + (size_t)16 * Hc;
        #pragma unroll
        for (int nd = 0; nd < 4; ++nd) {
            O[orowA + nd * 16 + lr] = (__bf16)(oA[nd][r] * invA);
            O[orowB + nd * 16 + lr] = (__bf16)(oB[nd][r] * invB);
        }
    }
}

// ---------------------------------------------------------------------------
// Fused residual + LayerNorm: y bf16. f32 master + bf16 copy out.
// ---------------------------------------------------------------------------
__global__ __launch_bounds__(256) void ln_kernel(
    const float* __restrict__ xr, const __bf16* __restrict__ y,
    const float* __restrict__ g, const float* __restrict__ beta,
    float* __restrict__ of, __bf16* __restrict__ oh)
{
    __shared__ float red[2][4];
    const int row = blockIdx.x, t = threadIdx.x;
    const int lane = t & 63, wave = t >> 6;
    const int idx = row * 256 + t;
    float4 a = ((const float4*)xr)[idx];
    bf16x4 cb = ((const bf16x4*)y)[idx];
    float4 v;
    v.x = a.x + (float)cb[0]; v.y = a.y + (float)cb[1];
    v.z = a.z + (float)cb[2]; v.w = a.w + (float)cb[3];
    float s1 = v.x + v.y + v.z + v.w;
    float s2 = v.x * v.x + v.y * v.y + v.z * v.z + v.w * v.w;
    #pragma unroll
    for (int off = 1; off < 64; off <<= 1) {
        s1 += __shfl_xor(s1, off);
        s2 += __shfl_xor(s2, off);
    }
    if (lane == 0) { red[0][wave] = s1; red[1][wave] = s2; }
    __syncthreads();
    s1 = red[0][0] + red[0][1] + red[0][2] + red[0][3];
    s2 = red[1][0] + red[1][1] + red[1][2] + red[1][3];
    const float mu   = s1 * (1.f / Hc);
    const float var  = s2 * (1.f / Hc) - mu * mu;
    const float rstd = rsqrtf(var + EPSc);
    float4 gg = ((const float4*)g)[t];
    float4 bb = ((const float4*)beta)[t];
    float4 r;
    r.x = (v.x - mu) * rstd * gg.x + bb.x;
    r.y = (v.y - mu) * rstd * gg.y + bb.y;
    r.z = (v.z - mu) * rstd * gg.z + bb.z;
    r.w = (v.w - mu) * rstd * gg.w + bb.w;
    ((float4*)of)[idx] = r;
    bf16x4 hh = { (__bf16)r.x, (__bf16)r.y, (__bf16)r.z, (__bf16)r.w };
    ((bf16x4*)oh)[idx] = hh;
}

// ---------------------------------------------------------------------------
extern "C" void kernel_launch(void* const* d_in, const int* in_sizes, int n_in,
                              void* d_out, int out_size, void* d_ws, size_t ws_size,
                              hipStream_t stream)
{
    const float* inp = (const float*)d_in[0];
    const float* pos = (const float*)d_in[1];
    const float* Wq  = (const float*)d_in[2];
    const float* bq  = (const float*)d_in[3];
    const float* Wk  = (const float*)d_in[4];
    const float* bk  = (const float*)d_in[5];
    const float* Wv  = (const float*)d_in[6];
    const float* bv  = (const float*)d_in[7];
    const float* Wo  = (const float*)d_in[8];
    const float* bo  = (const float*)d_in[9];
    const float* lng = (const float*)d_in[10];
    const float* lnb = (const float*)d_in[11];
    const float* W1  = (const float*)d_in[12];
    const float* b1  = (const float*)d_in[13];
    const float* W2  = (const float*)d_in[14];
    const float* b2  = (const float*)d_in[15];

    char* ws = (char*)d_ws;
    const size_t MB = 1u << 20;
    float*  src_f = (float*)(ws);              // 16 MB
    __bf16* src_h = (__bf16*)(ws + 16 * MB);   //  8 MB
    __bf16* src_l = (__bf16*)(ws + 24 * MB);   //  8 MB
    __bf16* qh    = (__bf16*)(ws + 32 * MB);   //  8 MB (head-major)
    __bf16* kh    = (__bf16*)(ws + 40 * MB);   //  8 MB
    __bf16* vv    = (__bf16*)(ws + 48 * MB);   //  8 MB
    __bf16* ctx   = (__bf16*)(ws + 56 * MB);   //  8 MB (row-major)
    __bf16* ql    = (__bf16*)(ws + 64 * MB);   //  8 MB (layer 0 only)
    __bf16* kl    = (__bf16*)(ws + 72 * MB);   //  8 MB
    __bf16* tmpb  = (__bf16*)(ws + 80 * MB);   //  8 MB (bf16 GEMM out; aliased below)
    __bf16* wq0h  = (__bf16*)(ws + 80 * MB);   //  2 MB (layer-0 split weights,
    __bf16* wq0l  = (__bf16*)(ws + 82 * MB);   //        dead before first tmpb use)
    __bf16* wk0h  = (__bf16*)(ws + 84 * MB);
    __bf16* wk0l  = (__bf16*)(ws + 86 * MB);
    __bf16* h1    = (__bf16*)(ws + 32 * MB);   // 32 MB alias (qh..ctx, dead by FFN)
    __bf16* wqT   = (__bf16*)(ws + 96 * MB);   // 12 MB each
    __bf16* wkT   = (__bf16*)(ws + 108 * MB);
    __bf16* wvT   = (__bf16*)(ws + 120 * MB);
    __bf16* woT   = (__bf16*)(ws + 132 * MB);
    __bf16* w1T   = (__bf16*)(ws + 144 * MB);  // 48 MB
    __bf16* w2T   = (__bf16*)(ws + 192 * MB);  // 48 MB ; total 240 MB

    const int M = Bc * Sc;  // 4096

    // layers 1-5 only for Wq/Wk (layer 0 uses the split wq0/wk0 path)
    wconv_kernel<<<dim3(16, 16, 5), 256, 0, stream>>>(Wq + (size_t)Hc * Hc,
                                                      wqT + (size_t)Hc * Hc, Hc, Hc);
    wconv_kernel<<<dim3(16, 16, 5), 256, 0, stream>>>(Wk + (size_t)Hc * Hc,
                                                      wkT + (size_t)Hc * Hc, Hc, Hc);
    wconv_kernel<<<dim3(16, 16, 6), 256, 0, stream>>>(Wv, wvT, Hc, Hc);
    wconv_kernel<<<dim3(16, 16, 6), 256, 0, stream>>>(Wo, woT, Hc, Hc);
    wconv_kernel<<<dim3(64, 16, 6), 256, 0, stream>>>(W1, w1T, Hc, PFc);
    wconv_kernel<<<dim3(16, 64, 6), 256, 0, stream>>>(W2, w2T, PFc, Hc);
    wconv2_kernel<<<dim3(16, 16), 256, 0, stream>>>(Wq, wq0h, wq0l, Hc, Hc);
    wconv2_kernel<<<dim3(16, 16), 256, 0, stream>>>(Wk, wk0h, wk0l, Hc, Hc);

    embed_kernel<<<2048, 256, 0, stream>>>(inp, pos, src_f, src_h, src_l);

    for (int l = 0; l < Lc; ++l) {
        const size_t wHH = (size_t)l * Hc * Hc;
        const size_t wH  = (size_t)l * Hc;
        if (l == 0) {
            QKV0S qa = { wq0h, wq0l, wk0h, wk0l, wvT, bq, bk, bv,
                         qh, ql, kh, kl, vv };
            qkv0s_kernel<<<dim3(24, 32), 256, 0, stream>>>(src_h, src_l, qa);
            attn_kernel<1, 1><<<512, 256, 0, stream>>>(qh, ql, kh, kl, vv, ctx);
        } else {
            QKVBT qa = { wqT + wHH, wkT + wHH, wvT + wHH, bq + wH, bk + wH, bv + wH,
                         qh, kh, vv };
            qkv_bt_kernel<<<dim3(24, 32), 256, 0, stream>>>(src_h, qa);
            attn_kernel<0, 2><<<512, 256, 0, stream>>>(qh, nullptr, kh, nullptr, vv, ctx);
        }
        gemm_bt_kernel<64, 1, false><<<dim3(8, 64), 256, 0, stream>>>(
            ctx, woT + wHH, bo + wH, tmpb, M, Hc, Hc);
        ln_kernel<<<M, 256, 0, stream>>>(src_f, tmpb, lng + wH, lnb + wH, src_f, src_h);
        gemm8p_kernel<1, true><<<dim3(16, 16), 512, 0, stream>>>(
            src_h, w1T + (size_t)l * Hc * PFc, b1 + (size_t)l * PFc, h1, M, PFc, Hc);
        gemm_bt_kernel<64, 1, false><<<dim3(8, 64), 256, 0, stream>>>(
            h1, w2T + (size_t)l * PFc * Hc, b2 + wH, tmpb, M, Hc, PFc);
        float* dst = (l == Lc - 1) ? (float*)d_out : src_f;
        ln_kernel<<<M, 256, 0, stream>>>(src_f, tmpb, lng + wH, lnb + wH, dst, src_h);
    }
}